// Round 3
// baseline (186.453 us; speedup 1.0000x reference)
//
#include <hip/hip_runtime.h>
#include <math.h>

// Problem constants (B=32, S=1024, H=512, D=2H=1024)
#define B 32
#define S 1024
#define D 1024
#define NCHUNK 32            // s-chunks per batch
#define CROWS (S / NCHUNK)   // 32 rows per chunk
#define WROWS (CROWS / 4)    // 8 rows per wave
#define THR 10.0f            // deferred-max threshold (values bounded by e^10)

// Workspace layout (floats):
#define WS_U      0                       // u[1024] = Wh^T v (atomic accum, memset to 0)
#define WS_CSC    1024                    // cscale = v·Wc
#define WS_CNT    1088                    // 32 int counters (zeroed by prep)
#define WS_SCORE  2048                    // score[B*S]
#define WS_ML     (WS_SCORE + B * S)      // (m,l) per (b,chunk): B*NCHUNK*2
#define WS_CTX    (WS_ML + B * NCHUNK * 2) // ctx partials: B*NCHUNK*D

__device__ inline float wave_reduce_sum(float v) {
    #pragma unroll
    for (int off = 32; off > 0; off >>= 1) v += __shfl_xor(v, off, 64);
    return v;
}

// Kernel 1: u[d] = sum_e v[e]*Wh[e,d] via e-split + atomicAdd (needs u zeroed).
// Block 128 additionally zeroes the finalize counters and computes cscale=v·Wc.
// grid = 129 blocks x 256 threads.
__global__ __launch_bounds__(256) void prep_kernel(
    const float* __restrict__ Wh, const float* __restrict__ Wc,
    const float* __restrict__ v, float* __restrict__ ws) {
    int blk = blockIdx.x, tid = threadIdx.x;
    if (blk == 128) {
        if (tid < B) ((int*)(ws + WS_CNT))[tid] = 0;
        float p = 0.f;
        #pragma unroll
        for (int k = 0; k < 4; ++k) { int i = tid + k * 256; p += v[i] * Wc[i]; }
        __shared__ float red[256];
        red[tid] = p; __syncthreads();
        for (int s = 128; s > 0; s >>= 1) {
            if (tid < s) red[tid] += red[tid + s];
            __syncthreads();
        }
        if (tid == 0) ws[WS_CSC] = red[0];
        return;
    }
    int dchunk = blk >> 5, echunk = blk & 31;
    int d = dchunk * 256 + tid, e0 = echunk * 32;
    float acc = 0.f;
    #pragma unroll 8
    for (int e = e0; e < e0 + 32; ++e)
        acc += v[e] * Wh[e * D + d];
    atomicAdd(&ws[WS_U + d], acc);
}

// Kernel 2: single enc pass. score = enc·u + cov*cscale (dec_feat dropped:
// per-b constant, softmax shift-invariant). Deferred-max online softmax,
// pairwise rows for ILP. Last block per batch finalizes in-place.
// grid = (NCHUNK, B) x 256 threads (4 waves x WROWS rows).
__global__ __launch_bounds__(256) void fused_kernel(
    const float4* __restrict__ enc4, const float* __restrict__ cov,
    const float* __restrict__ mask, float* __restrict__ ws,
    float* __restrict__ out) {
    int chunk = blockIdx.x, b = blockIdx.y;
    int tid = threadIdx.x, wave = tid >> 6, lane = tid & 63;

    __shared__ float lds_ctx[4][D];
    __shared__ float lds_ml[4][2];

    // lane's u slice lives in registers for the whole kernel (L2-hot 4KB)
    const float4* u4 = (const float4*)(ws + WS_U);
    float4 uv0 = u4[lane * 4 + 0], uv1 = u4[lane * 4 + 1];
    float4 uv2 = u4[lane * 4 + 2], uv3 = u4[lane * 4 + 3];
    float cscale = ws[WS_CSC];

    float m = -INFINITY, l = 0.f;
    float4 c0 = make_float4(0, 0, 0, 0), c1 = c0, c2 = c0, c3 = c0;

    int s_base = chunk * CROWS + wave * WROWS;
    for (int r = 0; r < WROWS; r += 2) {
        int idxA = b * S + s_base + r;
        int idxB = idxA + 1;
        size_t roA = (size_t)idxA * 256 + lane * 4;
        size_t roB = (size_t)idxB * 256 + lane * 4;
        float4 a0 = enc4[roA + 0], a1 = enc4[roA + 1], a2 = enc4[roA + 2], a3 = enc4[roA + 3];
        float4 b0 = enc4[roB + 0], b1 = enc4[roB + 1], b2 = enc4[roB + 2], b3 = enc4[roB + 3];
        float accA = a0.x * uv0.x + a0.y * uv0.y + a0.z * uv0.z + a0.w * uv0.w
                   + a1.x * uv1.x + a1.y * uv1.y + a1.z * uv1.z + a1.w * uv1.w
                   + a2.x * uv2.x + a2.y * uv2.y + a2.z * uv2.z + a2.w * uv2.w
                   + a3.x * uv3.x + a3.y * uv3.y + a3.z * uv3.z + a3.w * uv3.w;
        float accB = b0.x * uv0.x + b0.y * uv0.y + b0.z * uv0.z + b0.w * uv0.w
                   + b1.x * uv1.x + b1.y * uv1.y + b1.z * uv1.z + b1.w * uv1.w
                   + b2.x * uv2.x + b2.y * uv2.y + b2.z * uv2.z + b2.w * uv2.w
                   + b3.x * uv3.x + b3.y * uv3.y + b3.z * uv3.z + b3.w * uv3.w;
        // two independent butterfly reduces -> interleaved by scheduler
        #pragma unroll
        for (int off = 32; off > 0; off >>= 1) {
            accA += __shfl_xor(accA, off, 64);
            accB += __shfl_xor(accB, off, 64);
        }
        float scA = accA + cov[idxA] * cscale;
        float scB = accB + cov[idxB] * cscale;
        if (lane == 0) {
            ws[WS_SCORE + idxA] = scA;
            ws[WS_SCORE + idxB] = scB;
        }
        float mx = fmaxf(scA, scB);
        if (mx > m + THR) {               // wave-uniform, almost never taken
            float scl = __expf(m - mx);   // m=-inf first pair -> 0
            l *= scl;
            c0.x *= scl; c0.y *= scl; c0.z *= scl; c0.w *= scl;
            c1.x *= scl; c1.y *= scl; c1.z *= scl; c1.w *= scl;
            c2.x *= scl; c2.y *= scl; c2.z *= scl; c2.w *= scl;
            c3.x *= scl; c3.y *= scl; c3.z *= scl; c3.w *= scl;
            m = mx;
        }
        float eA = __expf(scA - m) * mask[idxA];
        float eB = __expf(scB - m) * mask[idxB];
        l += eA + eB;
        c0.x += eA * a0.x + eB * b0.x; c0.y += eA * a0.y + eB * b0.y;
        c0.z += eA * a0.z + eB * b0.z; c0.w += eA * a0.w + eB * b0.w;
        c1.x += eA * a1.x + eB * b1.x; c1.y += eA * a1.y + eB * b1.y;
        c1.z += eA * a1.z + eB * b1.z; c1.w += eA * a1.w + eB * b1.w;
        c2.x += eA * a2.x + eB * b2.x; c2.y += eA * a2.y + eB * b2.y;
        c2.z += eA * a2.z + eB * b2.z; c2.w += eA * a2.w + eB * b2.w;
        c3.x += eA * a3.x + eB * b3.x; c3.y += eA * a3.y + eB * b3.y;
        c3.z += eA * a3.z + eB * b3.z; c3.w += eA * a3.w + eB * b3.w;
    }

    // Cross-wave combine via LDS
    {
        float4* lc = (float4*)lds_ctx[wave];
        lc[lane * 4 + 0] = c0; lc[lane * 4 + 1] = c1;
        lc[lane * 4 + 2] = c2; lc[lane * 4 + 3] = c3;
        if (lane == 0) { lds_ml[wave][0] = m; lds_ml[wave][1] = l; }
    }
    __syncthreads();
    {
        float m0 = lds_ml[0][0], m1 = lds_ml[1][0], m2 = lds_ml[2][0], m3 = lds_ml[3][0];
        float mc = fmaxf(fmaxf(m0, m1), fmaxf(m2, m3));
        float f0 = __expf(m0 - mc), f1 = __expf(m1 - mc);
        float f2 = __expf(m2 - mc), f3 = __expf(m3 - mc);
        float lc = lds_ml[0][1] * f0 + lds_ml[1][1] * f1 + lds_ml[2][1] * f2 + lds_ml[3][1] * f3;
        float4 t0 = ((float4*)lds_ctx[0])[tid];
        float4 t1 = ((float4*)lds_ctx[1])[tid];
        float4 t2 = ((float4*)lds_ctx[2])[tid];
        float4 t3 = ((float4*)lds_ctx[3])[tid];
        float4 a;
        a.x = f0 * t0.x + f1 * t1.x + f2 * t2.x + f3 * t3.x;
        a.y = f0 * t0.y + f1 * t1.y + f2 * t2.y + f3 * t3.y;
        a.z = f0 * t0.z + f1 * t1.z + f2 * t2.z + f3 * t3.z;
        a.w = f0 * t0.w + f1 * t1.w + f2 * t2.w + f3 * t3.w;
        ((float4*)(ws + WS_CTX))[(b * NCHUNK + chunk) * 256 + tid] = a;
        if (tid == 0) {
            ws[WS_ML + (b * NCHUNK + chunk) * 2 + 0] = mc;
            ws[WS_ML + (b * NCHUNK + chunk) * 2 + 1] = lc;
        }
    }

    // Last block of this batch finalizes (device-scope fence + counter)
    __threadfence();
    __shared__ int is_last;
    if (tid == 0) {
        int old = atomicAdd(&((int*)(ws + WS_CNT))[b], 1);
        is_last = (old == NCHUNK - 1);
    }
    __syncthreads();
    if (!is_last) return;
    __threadfence();

    const float* ml = ws + WS_ML + b * NCHUNK * 2;
    float m_g = -INFINITY;
    #pragma unroll 8
    for (int c = 0; c < NCHUNK; ++c) m_g = fmaxf(m_g, ml[2 * c]);
    float l_g = 0.f;
    #pragma unroll 8
    for (int c = 0; c < NCHUNK; ++c) l_g += __expf(ml[2 * c] - m_g) * ml[2 * c + 1];
    float inv = 1.0f / l_g;

    __shared__ float fsc[NCHUNK];
    if (tid < NCHUNK) fsc[tid] = __expf(ml[2 * tid] - m_g);
    __syncthreads();

    // context output
    {
        float4 a = make_float4(0, 0, 0, 0);
        #pragma unroll 8
        for (int c = 0; c < NCHUNK; ++c) {
            float f = fsc[c];
            float4 p = ((const float4*)(ws + WS_CTX))[(b * NCHUNK + c) * 256 + tid];
            a.x += f * p.x; a.y += f * p.y; a.z += f * p.z; a.w += f * p.w;
        }
        a.x *= inv; a.y *= inv; a.z *= inv; a.w *= inv;
        ((float4*)out)[b * 256 + tid] = a;
    }
    // w and coverage_new outputs
    #pragma unroll
    for (int k = 0; k < 4; ++k) {
        int idx = b * S + tid + k * 256;
        float w = __expf(ws[WS_SCORE + idx] - m_g) * mask[idx] * inv;
        out[B * D + idx] = w;
        out[2 * B * D + idx] = cov[idx] + w;
    }
}

extern "C" void kernel_launch(void* const* d_in, const int* in_sizes, int n_in,
                              void* d_out, int out_size, void* d_ws, size_t ws_size,
                              hipStream_t stream) {
    const float* enc   = (const float*)d_in[2];
    const float* mask  = (const float*)d_in[3];
    const float* cov   = (const float*)d_in[4];
    const float* Wh    = (const float*)d_in[5];
    const float* Wc    = (const float*)d_in[8];
    const float* v     = (const float*)d_in[9];
    float* out = (float*)d_out;
    float* ws  = (float*)d_ws;

    // zero only the atomic-accumulated u vector (4 KB)
    hipMemsetAsync(ws, 0, (D) * sizeof(float), stream);

    prep_kernel<<<129, 256, 0, stream>>>(Wh, Wc, v, ws);
    fused_kernel<<<dim3(NCHUNK, B), 256, 0, stream>>>(
        (const float4*)enc, cov, mask, ws, out);
}

// Round 4
// 41.636 us; speedup vs baseline: 4.4782x; 4.4782x over previous
//
#include <hip/hip_runtime.h>
#include <math.h>

// Problem constants (B=32, S=1024, H=512, D=2H=1024)
#define B 32
#define S 1024
#define D 1024
#define NCHUNK 32            // s-chunks per batch
#define CROWS (S / NCHUNK)   // 32 rows per chunk
#define WROWS (CROWS / 4)    // 8 rows per wave
#define THR 10.0f            // deferred-max threshold (values bounded by e^10)

// Workspace layout (floats):
#define WS_U      0                        // u[1024] = Wh^T v (atomic accum, memset 0)
#define WS_CSC    1024                     // cscale = v·Wc
#define WS_SCORE  2048                     // score[B*S]
#define WS_ML     (WS_SCORE + B * S)       // (m,l) per (b,chunk): B*NCHUNK*2
#define WS_CTX    (WS_ML + B * NCHUNK * 2) // ctx partials: B*NCHUNK*D

// Kernel 1: u[d] = sum_e v[e]*Wh[e,d] via e-split + atomicAdd (u pre-zeroed).
// Block 128 computes cscale = v·Wc.  grid = 129 x 256.
__global__ __launch_bounds__(256) void prep_kernel(
    const float* __restrict__ Wh, const float* __restrict__ Wc,
    const float* __restrict__ v, float* __restrict__ ws) {
    int blk = blockIdx.x, tid = threadIdx.x;
    if (blk == 128) {
        float p = 0.f;
        #pragma unroll
        for (int k = 0; k < 4; ++k) { int i = tid + k * 256; p += v[i] * Wc[i]; }
        __shared__ float red[256];
        red[tid] = p; __syncthreads();
        for (int s = 128; s > 0; s >>= 1) {
            if (tid < s) red[tid] += red[tid + s];
            __syncthreads();
        }
        if (tid == 0) ws[WS_CSC] = red[0];
        return;
    }
    int dchunk = blk >> 5, echunk = blk & 31;
    int d = dchunk * 256 + tid, e0 = echunk * 32;
    float acc = 0.f;
    #pragma unroll 8
    for (int e = e0; e < e0 + 32; ++e)
        acc += v[e] * Wh[e * D + d];
    atomicAdd(&ws[WS_U + d], acc);
}

// Kernel 2: single enc pass. score = enc·u + cov*cscale (dec_feat dropped:
// constant per batch, softmax shift-invariant). Deferred-max online softmax,
// pairwise rows for ILP. Emits per-(b,chunk) partial (m, l, ctx[D]).
// grid = (NCHUNK, B) x 256 (4 waves x WROWS rows). NO fences, NO atomics.
__global__ __launch_bounds__(256) void fused_kernel(
    const float4* __restrict__ enc4, const float* __restrict__ cov,
    const float* __restrict__ mask, float* __restrict__ ws) {
    int chunk = blockIdx.x, b = blockIdx.y;
    int tid = threadIdx.x, wave = tid >> 6, lane = tid & 63;

    __shared__ float lds_ctx[4][D];
    __shared__ float lds_ml[4][2];

    // lane's u slice lives in registers for the whole kernel (L2-hot 4KB)
    const float4* u4 = (const float4*)(ws + WS_U);
    float4 uv0 = u4[lane * 4 + 0], uv1 = u4[lane * 4 + 1];
    float4 uv2 = u4[lane * 4 + 2], uv3 = u4[lane * 4 + 3];
    float cscale = ws[WS_CSC];

    float m = -INFINITY, l = 0.f;
    float4 c0 = make_float4(0, 0, 0, 0), c1 = c0, c2 = c0, c3 = c0;

    int s_base = chunk * CROWS + wave * WROWS;
    for (int r = 0; r < WROWS; r += 2) {
        int idxA = b * S + s_base + r;
        int idxB = idxA + 1;
        size_t roA = (size_t)idxA * 256 + lane * 4;
        size_t roB = (size_t)idxB * 256 + lane * 4;
        float4 a0 = enc4[roA + 0], a1 = enc4[roA + 1], a2 = enc4[roA + 2], a3 = enc4[roA + 3];
        float4 b0 = enc4[roB + 0], b1 = enc4[roB + 1], b2 = enc4[roB + 2], b3 = enc4[roB + 3];
        float accA = a0.x * uv0.x + a0.y * uv0.y + a0.z * uv0.z + a0.w * uv0.w
                   + a1.x * uv1.x + a1.y * uv1.y + a1.z * uv1.z + a1.w * uv1.w
                   + a2.x * uv2.x + a2.y * uv2.y + a2.z * uv2.z + a2.w * uv2.w
                   + a3.x * uv3.x + a3.y * uv3.y + a3.z * uv3.z + a3.w * uv3.w;
        float accB = b0.x * uv0.x + b0.y * uv0.y + b0.z * uv0.z + b0.w * uv0.w
                   + b1.x * uv1.x + b1.y * uv1.y + b1.z * uv1.z + b1.w * uv1.w
                   + b2.x * uv2.x + b2.y * uv2.y + b2.z * uv2.z + b2.w * uv2.w
                   + b3.x * uv3.x + b3.y * uv3.y + b3.z * uv3.z + b3.w * uv3.w;
        // two independent butterfly reduces -> interleaved by scheduler
        #pragma unroll
        for (int off = 32; off > 0; off >>= 1) {
            accA += __shfl_xor(accA, off, 64);
            accB += __shfl_xor(accB, off, 64);
        }
        float scA = accA + cov[idxA] * cscale;
        float scB = accB + cov[idxB] * cscale;
        if (lane == 0) {
            ws[WS_SCORE + idxA] = scA;
            ws[WS_SCORE + idxB] = scB;
        }
        float mx = fmaxf(scA, scB);
        if (mx > m + THR) {               // wave-uniform, almost never taken
            float scl = __expf(m - mx);   // m=-inf first pair -> 0
            l *= scl;
            c0.x *= scl; c0.y *= scl; c0.z *= scl; c0.w *= scl;
            c1.x *= scl; c1.y *= scl; c1.z *= scl; c1.w *= scl;
            c2.x *= scl; c2.y *= scl; c2.z *= scl; c2.w *= scl;
            c3.x *= scl; c3.y *= scl; c3.z *= scl; c3.w *= scl;
            m = mx;
        }
        float eA = __expf(scA - m) * mask[idxA];
        float eB = __expf(scB - m) * mask[idxB];
        l += eA + eB;
        c0.x += eA * a0.x + eB * b0.x; c0.y += eA * a0.y + eB * b0.y;
        c0.z += eA * a0.z + eB * b0.z; c0.w += eA * a0.w + eB * b0.w;
        c1.x += eA * a1.x + eB * b1.x; c1.y += eA * a1.y + eB * b1.y;
        c1.z += eA * a1.z + eB * b1.z; c1.w += eA * a1.w + eB * b1.w;
        c2.x += eA * a2.x + eB * b2.x; c2.y += eA * a2.y + eB * b2.y;
        c2.z += eA * a2.z + eB * b2.z; c2.w += eA * a2.w + eB * b2.w;
        c3.x += eA * a3.x + eB * b3.x; c3.y += eA * a3.y + eB * b3.y;
        c3.z += eA * a3.z + eB * b3.z; c3.w += eA * a3.w + eB * b3.w;
    }

    // Cross-wave combine via LDS
    {
        float4* lc = (float4*)lds_ctx[wave];
        lc[lane * 4 + 0] = c0; lc[lane * 4 + 1] = c1;
        lc[lane * 4 + 2] = c2; lc[lane * 4 + 3] = c3;
        if (lane == 0) { lds_ml[wave][0] = m; lds_ml[wave][1] = l; }
    }
    __syncthreads();
    {
        float m0 = lds_ml[0][0], m1 = lds_ml[1][0], m2 = lds_ml[2][0], m3 = lds_ml[3][0];
        float mc = fmaxf(fmaxf(m0, m1), fmaxf(m2, m3));
        float f0 = __expf(m0 - mc), f1 = __expf(m1 - mc);
        float f2 = __expf(m2 - mc), f3 = __expf(m3 - mc);
        float lc = lds_ml[0][1] * f0 + lds_ml[1][1] * f1 + lds_ml[2][1] * f2 + lds_ml[3][1] * f3;
        float4 t0 = ((float4*)lds_ctx[0])[tid];
        float4 t1 = ((float4*)lds_ctx[1])[tid];
        float4 t2 = ((float4*)lds_ctx[2])[tid];
        float4 t3 = ((float4*)lds_ctx[3])[tid];
        float4 a;
        a.x = f0 * t0.x + f1 * t1.x + f2 * t2.x + f3 * t3.x;
        a.y = f0 * t0.y + f1 * t1.y + f2 * t2.y + f3 * t3.y;
        a.z = f0 * t0.z + f1 * t1.z + f2 * t2.z + f3 * t3.z;
        a.w = f0 * t0.w + f1 * t1.w + f2 * t2.w + f3 * t3.w;
        ((float4*)(ws + WS_CTX))[(b * NCHUNK + chunk) * 256 + tid] = a;
        if (tid == 0) {
            ws[WS_ML + (b * NCHUNK + chunk) * 2 + 0] = mc;
            ws[WS_ML + (b * NCHUNK + chunk) * 2 + 1] = lc;
        }
    }
}

// Kernel 3: finalize. grid = (5, B).
// x<4: combine ctx partials (256 d's each). x==4: write w and coverage_new.
__global__ __launch_bounds__(256) void finalize_kernel(
    const float* __restrict__ mask, const float* __restrict__ cov,
    const float* __restrict__ ws, float* __restrict__ out) {
    int part = blockIdx.x, b = blockIdx.y, tid = threadIdx.x;
    const float* ml = ws + WS_ML + b * NCHUNK * 2;
    float m_g = -INFINITY;
    #pragma unroll 8
    for (int c = 0; c < NCHUNK; ++c) m_g = fmaxf(m_g, ml[2 * c]);
    float l_g = 0.f;
    #pragma unroll 8
    for (int c = 0; c < NCHUNK; ++c) l_g += __expf(ml[2 * c] - m_g) * ml[2 * c + 1];
    float inv = 1.0f / l_g;

    if (part < 4) {
        int d = part * 256 + tid;
        float a = 0.f;
        #pragma unroll 8
        for (int c = 0; c < NCHUNK; ++c)
            a += __expf(ml[2 * c] - m_g) * ws[WS_CTX + (size_t)(b * NCHUNK + c) * D + d];
        out[b * D + d] = a * inv;
    } else {
        #pragma unroll
        for (int k = 0; k < 4; ++k) {
            int idx = b * S + tid + k * 256;
            float w = __expf(ws[WS_SCORE + idx] - m_g) * mask[idx] * inv;
            out[B * D + idx] = w;                  // attention weights
            out[2 * B * D + idx] = cov[idx] + w;   // coverage_new
        }
    }
}

extern "C" void kernel_launch(void* const* d_in, const int* in_sizes, int n_in,
                              void* d_out, int out_size, void* d_ws, size_t ws_size,
                              hipStream_t stream) {
    const float* enc   = (const float*)d_in[2];
    const float* mask  = (const float*)d_in[3];
    const float* cov   = (const float*)d_in[4];
    const float* Wh    = (const float*)d_in[5];
    const float* Wc    = (const float*)d_in[8];
    const float* v     = (const float*)d_in[9];
    float* out = (float*)d_out;
    float* ws  = (float*)d_ws;

    // zero only the atomic-accumulated u vector (4 KB)
    hipMemsetAsync(ws, 0, D * sizeof(float), stream);

    prep_kernel<<<129, 256, 0, stream>>>(Wh, Wc, v, ws);
    fused_kernel<<<dim3(NCHUNK, B), 256, 0, stream>>>(
        (const float4*)enc, cov, mask, ws);
    finalize_kernel<<<dim3(5, B), 256, 0, stream>>>(mask, cov, ws, out);
}